// Round 10
// baseline (329.469 us; speedup 1.0000x reference)
//
#include <hip/hip_runtime.h>
#include <hip/hip_fp16.h>

// GCN 3->32->32->1, N=100K, E=6.4M (+self loops).
// R11-R16 synthesis: k_l2 floor tracks GATHER LANE-REQUESTS, not bytes,
//   not L2 locality, not dep chains: 72.5us = ~1 divergent lane-request
//   /cyc/CU at 8 requests/edge (8 lanes x 8B). R16 (int4 csr + LDS W2,
//   -40% ancillary VMEM) moved it only -2us -> coalesced requests cheap.
// R17: halve requests/edge: each gather instruction covers TWO edges --
//   lanes 0-3 read the 4x uint4 (16B) quarters of the even edge's row,
//   lanes 4-7 the odd edge's. 4 requests/edge, row fetched by 4 contiguous
//   16B lanes (perfect line coalescing). TLP unchanged (800K thr; R10's
//   mistake avoided). Combine banks via shfl_xor(4). Discriminator:
//   lane-request model -> ~50us; line-miss model -> unchanged (then k_l2
//   is at HW floor, pivot to sorts).
// R18: resubmit of R17 unchanged — prior round died to container infra
//   failure (no measurement; kernel re-audited for OOB/alignment, sound).
// Carried: fp16 g table, LDS-staged W2/b2/W3 epilogue, int4 csr loads,
//   fused k_sort, node-parallel layers, zero global atomics.

#define BLK 256
#define BLK2 512         // k_bsort / k_sort block size
#define SB 1280          // chunks; SB*CHUNK == E exactly
#define CHUNK 5000
#define BKT 128          // nodes per bucket
#define NBKT 782         // ceil(100000/128)
#define MAXNB 1024       // scanB width >= NBKT
#define BUFSZ 10240      // k_sort bucket buffer (mean 8192 + 22 sigma)

// ---- pass 1: per-chunk histogram over dst buckets (LDS, int4 loads)
__global__ void k_hist(const int* __restrict__ dst, int* __restrict__ hist, int E) {
    __shared__ int lh[NBKT];
    for (int b = threadIdx.x; b < NBKT; b += blockDim.x) lh[b] = 0;
    __syncthreads();
    int beg = blockIdx.x * CHUNK;
    int end = min(E, beg + CHUNK);
    int nq = (end - beg) >> 2;                    // full int4 quads
    const int4* d4 = (const int4*)(dst + beg);
    for (int i = threadIdx.x; i < nq; i += blockDim.x) {
        int4 d = d4[i];
        atomicAdd(&lh[d.x >> 7], 1);
        atomicAdd(&lh[d.y >> 7], 1);
        atomicAdd(&lh[d.z >> 7], 1);
        atomicAdd(&lh[d.w >> 7], 1);
    }
    for (int e = beg + (nq << 2) + threadIdx.x; e < end; e += blockDim.x)
        atomicAdd(&lh[dst[e] >> 7], 1);
    __syncthreads();
    for (int b = threadIdx.x; b < NBKT; b += blockDim.x)
        hist[(size_t)blockIdx.x * NBKT + b] = lh[b];
}

// ---- scan A: per bucket, exclusive-scan its SB chunk-counts (shfl, 5 items/thr)
__global__ void k_scanA(int* __restrict__ hist, int* __restrict__ btot, int NB) {
    int b = blockIdx.x, t = threadIdx.x;          // 256 threads * 5 items = 1280
    int base = t * 5;
    int v0 = hist[(size_t)(base + 0) * NB + b];
    int v1 = hist[(size_t)(base + 1) * NB + b];
    int v2 = hist[(size_t)(base + 2) * NB + b];
    int v3 = hist[(size_t)(base + 3) * NB + b];
    int v4 = hist[(size_t)(base + 4) * NB + b];
    int s = v0 + v1 + v2 + v3 + v4;
    int lane = t & 63, w = t >> 6;
    int x = s;
#pragma unroll
    for (int off = 1; off < 64; off <<= 1) {
        int u = __shfl_up(x, off, 64);
        if (lane >= off) x += u;
    }
    __shared__ int wsum[4];
    if (lane == 63) wsum[w] = x;
    __syncthreads();
    int woff = 0;
    for (int k = 0; k < 4; k++) woff += (k < w) ? wsum[k] : 0;
    int run = woff + x - s;                       // exclusive prefix for item 0
    hist[(size_t)(base + 0) * NB + b] = run;  run += v0;
    hist[(size_t)(base + 1) * NB + b] = run;  run += v1;
    hist[(size_t)(base + 2) * NB + b] = run;  run += v2;
    hist[(size_t)(base + 3) * NB + b] = run;  run += v3;
    hist[(size_t)(base + 4) * NB + b] = run;  run += v4;
    if (t == 255) btot[b] = run;
}

// ---- scan B: exclusive-scan bucket totals -> bucket base offsets
__global__ void k_scanB(const int* __restrict__ btot, int* __restrict__ bbase,
                        int NB, int E) {
    __shared__ int sh[MAXNB];
    int t = threadIdx.x;
    int v = (t < NB) ? btot[t] : 0;
    sh[t] = v;
    __syncthreads();
    for (int off = 1; off < MAXNB; off <<= 1) {
        int u = (t >= off) ? sh[t - off] : 0;
        __syncthreads();
        sh[t] += u;
        __syncthreads();
    }
    if (t < NB) bbase[t] = sh[t] - v;
    if (t == 0) bbase[NB] = E;
}

// ---- pass 2: LDS chunk-sort by bucket, full-lane sorted-order streaming.
// Chunk counts from hist-row differencing (scanA in-place prefixes).
__global__ void k_bsort(const int* __restrict__ src, const int* __restrict__ dst,
                        const int* __restrict__ hist, const int* __restrict__ btot,
                        const int* __restrict__ bbase,
                        unsigned int* __restrict__ packed, int E) {
    __shared__ unsigned int bufB[CHUNK];          // 20 KB
    __shared__ unsigned short binarr2[CHUNK];     // 10 KB (bucket of sorted pos)
    __shared__ int cnt[NBKT];
    __shared__ int off[NBKT];
    __shared__ int cur[NBKT];
    __shared__ int gbase[NBKT];
    __shared__ int wsum[8];
    int t = threadIdx.x;
    int beg = blockIdx.x * CHUNK;
    int end = min(E, beg + CHUNK);
    int len = end - beg;
    int last = (blockIdx.x + 1 == gridDim.x);
    for (int b = t; b < NBKT; b += blockDim.x) {
        int my = hist[(size_t)blockIdx.x * NBKT + b];
        int nx = last ? btot[b] : hist[(size_t)(blockIdx.x + 1) * NBKT + b];
        cnt[b] = nx - my;
        gbase[b] = bbase[b] + my;
    }
    __syncthreads();
    // phase b: exclusive scan of 782 counts (2 items/thread, shfl, 8 waves)
    {
        int base = t * 2;
        int v0 = (base + 0 < NBKT) ? cnt[base + 0] : 0;
        int v1 = (base + 1 < NBKT) ? cnt[base + 1] : 0;
        int s = v0 + v1;
        int lane = t & 63, w = t >> 6;
        int x = s;
#pragma unroll
        for (int o = 1; o < 64; o <<= 1) {
            int u = __shfl_up(x, o, 64);
            if (lane >= o) x += u;
        }
        if (lane == 63) wsum[w] = x;
        __syncthreads();
        int woff = 0;
        for (int k = 0; k < 8; k++) woff += (k < w) ? wsum[k] : 0;
        int run = woff + x - s;
        if (base + 0 < NBKT) { off[base + 0] = run; cur[base + 0] = run; } run += v0;
        if (base + 1 < NBKT) { off[base + 1] = run; cur[base + 1] = run; } run += v1;
    }
    __syncthreads();
    // phase c: permute into bucket-grouped order
    for (int i = t; i < len; i += blockDim.x) {
        int d = dst[beg + i];
        int s = src[beg + i];
        int b = d >> 7;
        int pos = atomicAdd(&cur[b], 1);
        bufB[pos] = (unsigned)s | ((unsigned)(d & 127) << 17);
        binarr2[pos] = (unsigned short)b;
    }
    __syncthreads();
    // phase d: full-lane sorted-order write (runs are dest-contiguous)
    for (int i = t; i < len; i += blockDim.x) {
        int b = binarr2[i];
        packed[gbase[b] + i - off[b]] = bufB[i];
    }
}

// ---- fused: per-bucket 128-bin count + scan + dis/y4/rowptr + in-place
// node sort. 512 threads, fused load+count.
__global__ void k_sort(unsigned int* __restrict__ packed, const int* __restrict__ bbase,
                       const float* __restrict__ x, float* __restrict__ dis,
                       float4* __restrict__ y4, int* __restrict__ rowptr, int N, int E) {
    __shared__ unsigned int buf[BUFSZ];           // 40 KB
    __shared__ int cnt[BKT];
    __shared__ int cur[BKT];
    __shared__ int wsum[2];
    int b = blockIdx.x, t = threadIdx.x;
    int beg = bbase[b], end = bbase[b + 1];
    int len = end - beg;
    if (t < BKT) cnt[t] = 0;
    __syncthreads();
    // fused: load bucket into LDS + count bins in one pass
    for (int i = t; i < len; i += blockDim.x) {
        unsigned v = packed[beg + i];
        buf[i] = v;
        atomicAdd(&cnt[v >> 17], 1);
    }
    __syncthreads();
    // exclusive scan over 128 bins (threads 0..127, 2 waves)
    int v0 = 0, xs = 0;
    if (t < BKT) {
        v0 = cnt[t];
        xs = v0;
#pragma unroll
        for (int o = 1; o < 64; o <<= 1) {
            int u = __shfl_up(xs, o, 64);
            if ((t & 63) >= o) xs += u;
        }
        if ((t & 63) == 63) wsum[t >> 6] = xs;
    }
    __syncthreads();
    if (t < BKT) {
        int woff = (t >= 64) ? wsum[0] : 0;
        int excl = woff + xs - v0;
        cur[t] = excl;
        int gi = b * BKT + t;
        if (gi < N) {
            rowptr[gi] = beg + excl;
            float di = rsqrtf((float)v0 + 1.0f);  // + self loop
            dis[gi] = di;
            float4 y;
            y.x = di * x[3 * gi + 0];
            y.y = di * x[3 * gi + 1];
            y.z = di * x[3 * gi + 2];
            y.w = 0.0f;
            y4[gi] = y;
        }
    }
    __syncthreads();
    for (int i = t; i < len; i += blockDim.x) {
        unsigned vv = buf[i];
        int pos = atomicAdd(&cur[vv >> 17], 1);   // LDS atomic
        packed[beg + pos] = vv & 0x1FFFF;         // plain src id, node-sorted
    }
    if (b == 0 && t == 0) rowptr[N] = E;
}

// ---- layer 1: node-parallel, 32 lanes/node gather y4 (1.6MB, L2-resident)
__global__ void k_l1(const unsigned int* __restrict__ csr, const int* __restrict__ rowptr,
                     const float4* __restrict__ y4, const float* __restrict__ dis,
                     const float* __restrict__ W1, const float* __restrict__ b1,
                     __half* __restrict__ g, int N) {
    int t = blockIdx.x * blockDim.x + threadIdx.x;
    int i = t >> 5, j = t & 31;
    if (i >= N) return;
    int beg = rowptr[i], end = rowptr[i + 1];
    float ax = 0.f, ay = 0.f, az = 0.f;
    for (int e = beg + j; e < end; e += 32) {
        float4 yv = y4[csr[e]];
        ax += yv.x; ay += yv.y; az += yv.z;
    }
#pragma unroll
    for (int m = 16; m >= 1; m >>= 1) {
        ax += __shfl_xor(ax, m, 32);
        ay += __shfl_xor(ay, m, 32);
        az += __shfl_xor(az, m, 32);
    }
    float di = dis[i];
    float4 ys = y4[i];                               // self loop (pre-scaled)
    float a0 = di * (ax + ys.x);
    float a1 = di * (ay + ys.y);
    float a2 = di * (az + ys.z);
    float h = b1[j] + a0 * W1[j] + a1 * W1[32 + j] + a2 * W1[64 + j];
    g[(size_t)i * 32 + j] = __float2half(di * fmaxf(h, 0.f));
}

// unpack one uint4 (8 halves) and accumulate into 8 fp32 accumulators
__device__ __forceinline__ void acc8u(float* a, uint4 r) {
    const __half2* h = (const __half2*)&r;
#pragma unroll
    for (int k = 0; k < 4; k++) {
        float2 f = __half22float2(h[k]);
        a[2 * k]     += f.x;
        a[2 * k + 1] += f.y;
    }
}

// unpack one uint4 (8 halves) into 8 floats
__device__ __forceinline__ void unp8(float* a, uint4 r) {
    const __half2* h = (const __half2*)&r;
#pragma unroll
    for (int k = 0; k < 4; k++) {
        float2 f = __half22float2(h[k]);
        a[2 * k]     = f.x;
        a[2 * k + 1] = f.y;
    }
}

// ---- layer 2 (+L3 projection): 8 lanes/node; each gather instruction
// covers TWO edges: lanes 0-3 (hi=0) read the 4 uint4 quarters of the even
// edge's 64B row, lanes 4-7 (hi=1) the odd edge's. 4 lane-requests/edge
// (was 8), perfect line coalescing (4x16B contiguous per row). Two 8-float
// banks combined via shfl_xor(4). Epilogue: LDS W2/b2/W3, quarter-indexed
// shuffles.
__global__ void k_l2(const unsigned int* __restrict__ csr, const int* __restrict__ rowptr,
                     const __half* __restrict__ g, const float* __restrict__ dis,
                     const float* __restrict__ W2, const float* __restrict__ b2,
                     const float* __restrict__ W3, float* __restrict__ q, int N) {
    __shared__ float sW2[1024];                      // 4KB: [32 in][32 out]
    __shared__ float sb2[32];
    __shared__ float sW3[32];
    int tid = threadIdx.x;
    ((float4*)sW2)[tid] = ((const float4*)W2)[tid];  // 256 thr x 16B = 4KB
    if (tid < 32) { sb2[tid] = b2[tid]; sW3[tid] = W3[tid]; }
    __syncthreads();
    int t = blockIdx.x * blockDim.x + tid;
    int i = t >> 3, j = t & 7;
    if (i >= N) return;
    int jq = j & 3;                                  // row quarter owned (16B)
    int hi = j >> 2;                                 // 0: even edge, 1: odd edge
    int beg = rowptr[i], end = rowptr[i + 1];
    const uint4* g4 = (const uint4*)g;               // [N][4] x 16B quarters
    float A[8] = {0.f, 0.f, 0.f, 0.f, 0.f, 0.f, 0.f, 0.f};
    float B[8] = {0.f, 0.f, 0.f, 0.f, 0.f, 0.f, 0.f, 0.f};
    int e = beg;
    // head-peel to 4-edge (16B) alignment; single edges: hi=0 lanes only
    for (; e < end && (e & 3); e++) {
        if (!hi) { uint4 r = g4[(unsigned)csr[e] * 4 + jq]; acc8u(A, r); }
    }
    for (; e + 8 <= end; e += 8) {
        int4 ca = *(const int4*)(csr + e);           // slots 0..3 (aligned)
        int4 cb = *(const int4*)(csr + e + 4);       // slots 4..7
        int sA = hi ? ca.y : ca.x;                   // pair (0,1)
        int sB = hi ? ca.w : ca.z;                   // pair (2,3)
        int sC = hi ? cb.y : cb.x;                   // pair (4,5)
        int sD = hi ? cb.w : cb.z;                   // pair (6,7)
        uint4 r0 = g4[sA * 4 + jq];
        uint4 r1 = g4[sB * 4 + jq];
        uint4 r2 = g4[sC * 4 + jq];
        uint4 r3 = g4[sD * 4 + jq];
        acc8u(A, r0);
        acc8u(B, r1);
        acc8u(A, r2);
        acc8u(B, r3);
    }
    for (; e < end; e++) {
        if (!hi) { uint4 r = g4[(unsigned)csr[e] * 4 + jq]; acc8u(A, r); }
    }
    // combine banks + even/odd halves: lanes j and j^4 both end with the
    // full quarter-(j&3) sum
#pragma unroll
    for (int f = 0; f < 8; f++) {
        A[f] += B[f];
        A[f] += __shfl_xor(A[f], 4, 8);
    }
    float di = dis[i];
    uint4 rs = g4[(unsigned)i * 4 + jq];             // self-loop quarter
    float sf[8];
    unp8(sf, rs);
#pragma unroll
    for (int f = 0; f < 8; f++) A[f] = di * (A[f] + sf[f]);   // a[8*(j&3)+f]
    // W2 matmul from LDS: lane j -> outputs m=4j..4j+3.
    // input a[k]: quarter k>>3 lives in lane (k>>3), element k&7.
    int m = 4 * j;
    float4 bo = *(const float4*)&sb2[m];
    float o0 = bo.x, o1 = bo.y, o2 = bo.z, o3 = bo.w;
#pragma unroll
    for (int kl = 0; kl < 8; kl++) {
        int qsrc = kl >> 1;                          // quarter lane
        int eb = (kl & 1) * 4;                       // element base in quarter
        float x0 = __shfl(A[eb + 0], qsrc, 8);       // a[4kl+0]
        float x1 = __shfl(A[eb + 1], qsrc, 8);
        float x2 = __shfl(A[eb + 2], qsrc, 8);
        float x3 = __shfl(A[eb + 3], qsrc, 8);
        float4 w0 = *(const float4*)&sW2[(4 * kl + 0) * 32 + m];
        float4 w1 = *(const float4*)&sW2[(4 * kl + 1) * 32 + m];
        float4 w2 = *(const float4*)&sW2[(4 * kl + 2) * 32 + m];
        float4 w3 = *(const float4*)&sW2[(4 * kl + 3) * 32 + m];
        o0 = fmaf(x0, w0.x, fmaf(x1, w1.x, fmaf(x2, w2.x, fmaf(x3, w3.x, o0))));
        o1 = fmaf(x0, w0.y, fmaf(x1, w1.y, fmaf(x2, w2.y, fmaf(x3, w3.y, o1))));
        o2 = fmaf(x0, w0.z, fmaf(x1, w1.z, fmaf(x2, w2.z, fmaf(x3, w3.z, o2))));
        o3 = fmaf(x0, w0.w, fmaf(x1, w1.w, fmaf(x2, w2.w, fmaf(x3, w3.w, o3))));
    }
    float4 wv = *(const float4*)&sW3[m];
    float cc = fmaxf(o0, 0.f) * wv.x + fmaxf(o1, 0.f) * wv.y
             + fmaxf(o2, 0.f) * wv.z + fmaxf(o3, 0.f) * wv.w;
    cc += __shfl_xor(cc, 1, 8);
    cc += __shfl_xor(cc, 2, 8);
    cc += __shfl_xor(cc, 4, 8);
    if (j == 0) q[i] = di * cc;                      // q = dis * p
}

// ---- layer 3: node-parallel scalar q gathers (q 400KB, L2-resident)
__global__ void k_l3(const unsigned int* __restrict__ csr, const int* __restrict__ rowptr,
                     const float* __restrict__ q, const float* __restrict__ dis,
                     const float* __restrict__ b3, float* __restrict__ out, int N) {
    int t = blockIdx.x * blockDim.x + threadIdx.x;
    int i = t >> 5, j = t & 31;
    if (i >= N) return;
    int beg = rowptr[i], end = rowptr[i + 1];
    float acc = 0.f;
    for (int e = beg + j; e < end; e += 32)
        acc += q[csr[e]];
#pragma unroll
    for (int m = 16; m >= 1; m >>= 1)
        acc += __shfl_xor(acc, m, 32);
    if (j == 0) out[i] = dis[i] * (acc + q[i]) + b3[0];
}

extern "C" void kernel_launch(void* const* d_in, const int* in_sizes, int n_in,
                              void* d_out, int out_size, void* d_ws, size_t ws_size,
                              hipStream_t stream) {
    const float* x  = (const float*)d_in[0];
    const int*   ei = (const int*)d_in[1];
    const float* W1 = (const float*)d_in[2];
    const float* b1 = (const float*)d_in[3];
    const float* W2 = (const float*)d_in[4];
    const float* b2 = (const float*)d_in[5];
    const float* W3 = (const float*)d_in[6];
    const float* b3 = (const float*)d_in[7];
    float* out = (float*)d_out;

    int N = in_sizes[0] / 3;
    int E = in_sizes[1] / 2;
    const int* src = ei;
    const int* dst = ei + E;

    // workspace (all init done in-kernel; no memset needed), 256B-aligned carves
    char* w = (char*)d_ws;
#define CARVE(nbytes) w; w += (((size_t)(nbytes) + 255) & ~(size_t)255)
    int*   hist   = (int*)  CARVE((size_t)SB * NBKT * 4);   // 4.0 MB
    int*   btot   = (int*)  CARVE((size_t)MAXNB * 4);
    int*   bbase  = (int*)  CARVE((size_t)(MAXNB + 1) * 4);
    int*   rowptr = (int*)  CARVE((size_t)(N + 1) * 4);
    float* dis    = (float*)CARVE((size_t)N * 4);
    float* y4     = (float*)CARVE((size_t)N * 16);
    __half* g     = (__half*)CARVE((size_t)N * 32 * 2);     // 6.4 MB fp16
    float* q      = (float*)CARVE((size_t)N * 4);
    unsigned int* packed = (unsigned int*)CARVE((size_t)E * 4);  // 25.6 MB
#undef CARVE

    k_hist <<<SB, BLK, 0, stream>>>(dst, hist, E);
    k_scanA<<<NBKT, BLK, 0, stream>>>(hist, btot, NBKT);
    k_scanB<<<1, MAXNB, 0, stream>>>(btot, bbase, NBKT, E);
    k_bsort<<<SB, BLK2, 0, stream>>>(src, dst, hist, btot, bbase, packed, E);
    k_sort <<<NBKT, BLK2, 0, stream>>>(packed, bbase, x, dis, (float4*)y4, rowptr, N, E);

    long long tn = (long long)N * 32;
    unsigned gn = (unsigned)((tn + BLK - 1) / BLK);
    long long tn8 = (long long)N * 8;
    unsigned gn8 = (unsigned)((tn8 + BLK - 1) / BLK);
    k_l1<<<gn,  BLK, 0, stream>>>(packed, rowptr, (const float4*)y4, dis, W1, b1, g, N);
    k_l2<<<gn8, BLK, 0, stream>>>(packed, rowptr, g, dis, W2, b2, W3, q, N);
    k_l3<<<gn,  BLK, 0, stream>>>(packed, rowptr, q, dis, b3, out, N);
}

// Round 11
// 326.729 us; speedup vs baseline: 1.0084x; 1.0084x over previous
//
#include <hip/hip_runtime.h>
#include <hip/hip_fp16.h>

// GCN 3->32->32->1, N=100K, E=6.4M (+self loops).
// R17/R18 verdict: k_l2 floor is PER-LINE and doubly pinned — 221MB random
//   64B HBM fetches @ ~3.05 TB/s (random-granule ceiling ~= half streaming)
//   AND the L2-resident per-edge fill cost both give ~72us. Request-count,
//   locality, dep-chains all falsified as levers. k_l2 reverted to R16 form
//   (best measured 72.5us); no further k_l2 work.
// R19: pivot to the ~256us outside k_l2. k_bsort/k_sort proven occupancy-
//   sensitive (R14: 56->~40us via 8->24 waves/CU). Push 24->32 waves/CU:
//   CHUNK 5000->4000 (k_bsort LDS 42.8->36.6KB -> 4 blocks/CU; SB=1600,
//   shorter serial phases, +25% blocks; scanA 512thr x 4 guarded items),
//   BUFSZ 10240->9950 (k_sort LDS 40.8KB -> exactly 4/CU; 19.4-sigma
//   bucket-overflow margin).
// Carried: fp16 g, LDS W2/b2/W3 epilogue, int4 csr, 4 acc banks, fused
//   k_sort, hist-row-differencing k_bsort, zero global atomics.

#define BLK 256
#define BLK2 512         // k_bsort / k_sort / k_scanA block size
#define SB 1600          // chunks; SB*CHUNK == E exactly
#define CHUNK 4000
#define BKT 128          // nodes per bucket
#define NBKT 782         // ceil(100000/128)
#define MAXNB 1024       // scanB width >= NBKT
#define BUFSZ 9950       // k_sort bucket buffer (mean 8192 + 19.4 sigma)

// ---- pass 1: per-chunk histogram over dst buckets (LDS, int4 loads)
__global__ void k_hist(const int* __restrict__ dst, int* __restrict__ hist, int E) {
    __shared__ int lh[NBKT];
    for (int b = threadIdx.x; b < NBKT; b += blockDim.x) lh[b] = 0;
    __syncthreads();
    int beg = blockIdx.x * CHUNK;
    int end = min(E, beg + CHUNK);
    int nq = (end - beg) >> 2;                    // full int4 quads
    const int4* d4 = (const int4*)(dst + beg);
    for (int i = threadIdx.x; i < nq; i += blockDim.x) {
        int4 d = d4[i];
        atomicAdd(&lh[d.x >> 7], 1);
        atomicAdd(&lh[d.y >> 7], 1);
        atomicAdd(&lh[d.z >> 7], 1);
        atomicAdd(&lh[d.w >> 7], 1);
    }
    for (int e = beg + (nq << 2) + threadIdx.x; e < end; e += blockDim.x)
        atomicAdd(&lh[dst[e] >> 7], 1);
    __syncthreads();
    for (int b = threadIdx.x; b < NBKT; b += blockDim.x)
        hist[(size_t)blockIdx.x * NBKT + b] = lh[b];
}

// ---- scan A: per bucket, exclusive-scan its SB chunk-counts
// (512 threads x 4 guarded items = 2048 >= SB=1600)
__global__ void k_scanA(int* __restrict__ hist, int* __restrict__ btot, int NB) {
    int b = blockIdx.x, t = threadIdx.x;
    int base = t * 4;
    int v0 = (base + 0 < SB) ? hist[(size_t)(base + 0) * NB + b] : 0;
    int v1 = (base + 1 < SB) ? hist[(size_t)(base + 1) * NB + b] : 0;
    int v2 = (base + 2 < SB) ? hist[(size_t)(base + 2) * NB + b] : 0;
    int v3 = (base + 3 < SB) ? hist[(size_t)(base + 3) * NB + b] : 0;
    int s = v0 + v1 + v2 + v3;
    int lane = t & 63, w = t >> 6;
    int x = s;
#pragma unroll
    for (int off = 1; off < 64; off <<= 1) {
        int u = __shfl_up(x, off, 64);
        if (lane >= off) x += u;
    }
    __shared__ int wsum[8];
    if (lane == 63) wsum[w] = x;
    __syncthreads();
    int woff = 0;
    for (int k = 0; k < 8; k++) woff += (k < w) ? wsum[k] : 0;
    int run = woff + x - s;                       // exclusive prefix for item 0
    if (base + 0 < SB) hist[(size_t)(base + 0) * NB + b] = run;  run += v0;
    if (base + 1 < SB) hist[(size_t)(base + 1) * NB + b] = run;  run += v1;
    if (base + 2 < SB) hist[(size_t)(base + 2) * NB + b] = run;  run += v2;
    if (base + 3 < SB) hist[(size_t)(base + 3) * NB + b] = run;  run += v3;
    if (t == 511) btot[b] = run;
}

// ---- scan B: exclusive-scan bucket totals -> bucket base offsets
__global__ void k_scanB(const int* __restrict__ btot, int* __restrict__ bbase,
                        int NB, int E) {
    __shared__ int sh[MAXNB];
    int t = threadIdx.x;
    int v = (t < NB) ? btot[t] : 0;
    sh[t] = v;
    __syncthreads();
    for (int off = 1; off < MAXNB; off <<= 1) {
        int u = (t >= off) ? sh[t - off] : 0;
        __syncthreads();
        sh[t] += u;
        __syncthreads();
    }
    if (t < NB) bbase[t] = sh[t] - v;
    if (t == 0) bbase[NB] = E;
}

// ---- pass 2: LDS chunk-sort by bucket, full-lane sorted-order streaming.
// Chunk counts from hist-row differencing (scanA in-place prefixes).
// LDS 36.6KB -> 4 blocks/CU (32 waves).
__global__ void k_bsort(const int* __restrict__ src, const int* __restrict__ dst,
                        const int* __restrict__ hist, const int* __restrict__ btot,
                        const int* __restrict__ bbase,
                        unsigned int* __restrict__ packed, int E) {
    __shared__ unsigned int bufB[CHUNK];          // 16 KB
    __shared__ unsigned short binarr2[CHUNK];     // 8 KB (bucket of sorted pos)
    __shared__ int cnt[NBKT];
    __shared__ int off[NBKT];
    __shared__ int cur[NBKT];
    __shared__ int gbase[NBKT];
    __shared__ int wsum[8];
    int t = threadIdx.x;
    int beg = blockIdx.x * CHUNK;
    int end = min(E, beg + CHUNK);
    int len = end - beg;
    int last = (blockIdx.x + 1 == gridDim.x);
    for (int b = t; b < NBKT; b += blockDim.x) {
        int my = hist[(size_t)blockIdx.x * NBKT + b];
        int nx = last ? btot[b] : hist[(size_t)(blockIdx.x + 1) * NBKT + b];
        cnt[b] = nx - my;
        gbase[b] = bbase[b] + my;
    }
    __syncthreads();
    // phase b: exclusive scan of 782 counts (2 items/thread, shfl, 8 waves)
    {
        int base = t * 2;
        int v0 = (base + 0 < NBKT) ? cnt[base + 0] : 0;
        int v1 = (base + 1 < NBKT) ? cnt[base + 1] : 0;
        int s = v0 + v1;
        int lane = t & 63, w = t >> 6;
        int x = s;
#pragma unroll
        for (int o = 1; o < 64; o <<= 1) {
            int u = __shfl_up(x, o, 64);
            if (lane >= o) x += u;
        }
        if (lane == 63) wsum[w] = x;
        __syncthreads();
        int woff = 0;
        for (int k = 0; k < 8; k++) woff += (k < w) ? wsum[k] : 0;
        int run = woff + x - s;
        if (base + 0 < NBKT) { off[base + 0] = run; cur[base + 0] = run; } run += v0;
        if (base + 1 < NBKT) { off[base + 1] = run; cur[base + 1] = run; } run += v1;
    }
    __syncthreads();
    // phase c: permute into bucket-grouped order
    for (int i = t; i < len; i += blockDim.x) {
        int d = dst[beg + i];
        int s = src[beg + i];
        int b = d >> 7;
        int pos = atomicAdd(&cur[b], 1);
        bufB[pos] = (unsigned)s | ((unsigned)(d & 127) << 17);
        binarr2[pos] = (unsigned short)b;
    }
    __syncthreads();
    // phase d: full-lane sorted-order write (runs are dest-contiguous)
    for (int i = t; i < len; i += blockDim.x) {
        int b = binarr2[i];
        packed[gbase[b] + i - off[b]] = bufB[i];
    }
}

// ---- fused: per-bucket 128-bin count + scan + dis/y4/rowptr + in-place
// node sort. 512 threads, fused load+count. LDS 40.8KB -> 4 blocks/CU.
__global__ void k_sort(unsigned int* __restrict__ packed, const int* __restrict__ bbase,
                       const float* __restrict__ x, float* __restrict__ dis,
                       float4* __restrict__ y4, int* __restrict__ rowptr, int N, int E) {
    __shared__ unsigned int buf[BUFSZ];           // 38.9 KB
    __shared__ int cnt[BKT];
    __shared__ int cur[BKT];
    __shared__ int wsum[2];
    int b = blockIdx.x, t = threadIdx.x;
    int beg = bbase[b], end = bbase[b + 1];
    int len = end - beg;
    if (t < BKT) cnt[t] = 0;
    __syncthreads();
    // fused: load bucket into LDS + count bins in one pass
    for (int i = t; i < len; i += blockDim.x) {
        unsigned v = packed[beg + i];
        buf[i] = v;
        atomicAdd(&cnt[v >> 17], 1);
    }
    __syncthreads();
    // exclusive scan over 128 bins (threads 0..127, 2 waves)
    int v0 = 0, xs = 0;
    if (t < BKT) {
        v0 = cnt[t];
        xs = v0;
#pragma unroll
        for (int o = 1; o < 64; o <<= 1) {
            int u = __shfl_up(xs, o, 64);
            if ((t & 63) >= o) xs += u;
        }
        if ((t & 63) == 63) wsum[t >> 6] = xs;
    }
    __syncthreads();
    if (t < BKT) {
        int woff = (t >= 64) ? wsum[0] : 0;
        int excl = woff + xs - v0;
        cur[t] = excl;
        int gi = b * BKT + t;
        if (gi < N) {
            rowptr[gi] = beg + excl;
            float di = rsqrtf((float)v0 + 1.0f);  // + self loop
            dis[gi] = di;
            float4 y;
            y.x = di * x[3 * gi + 0];
            y.y = di * x[3 * gi + 1];
            y.z = di * x[3 * gi + 2];
            y.w = 0.0f;
            y4[gi] = y;
        }
    }
    __syncthreads();
    for (int i = t; i < len; i += blockDim.x) {
        unsigned vv = buf[i];
        int pos = atomicAdd(&cur[vv >> 17], 1);   // LDS atomic
        packed[beg + pos] = vv & 0x1FFFF;         // plain src id, node-sorted
    }
    if (b == 0 && t == 0) rowptr[N] = E;
}

// ---- layer 1: node-parallel, 32 lanes/node gather y4 (1.6MB, L2-resident)
__global__ void k_l1(const unsigned int* __restrict__ csr, const int* __restrict__ rowptr,
                     const float4* __restrict__ y4, const float* __restrict__ dis,
                     const float* __restrict__ W1, const float* __restrict__ b1,
                     __half* __restrict__ g, int N) {
    int t = blockIdx.x * blockDim.x + threadIdx.x;
    int i = t >> 5, j = t & 31;
    if (i >= N) return;
    int beg = rowptr[i], end = rowptr[i + 1];
    float ax = 0.f, ay = 0.f, az = 0.f;
    for (int e = beg + j; e < end; e += 32) {
        float4 yv = y4[csr[e]];
        ax += yv.x; ay += yv.y; az += yv.z;
    }
#pragma unroll
    for (int m = 16; m >= 1; m >>= 1) {
        ax += __shfl_xor(ax, m, 32);
        ay += __shfl_xor(ay, m, 32);
        az += __shfl_xor(az, m, 32);
    }
    float di = dis[i];
    float4 ys = y4[i];                               // self loop (pre-scaled)
    float a0 = di * (ax + ys.x);
    float a1 = di * (ay + ys.y);
    float a2 = di * (az + ys.z);
    float h = b1[j] + a0 * W1[j] + a1 * W1[32 + j] + a2 * W1[64 + j];
    g[(size_t)i * 32 + j] = __float2half(di * fmaxf(h, 0.f));
}

// unpack one uint2 (4 halves) and accumulate into 4 fp32 accumulators
__device__ __forceinline__ void acc4(float& c0, float& c1, float& c2, float& c3,
                                     uint2 r) {
    __half2 a = *(const __half2*)&r.x;
    __half2 b = *(const __half2*)&r.y;
    float2 fa = __half22float2(a);
    float2 fb = __half22float2(b);
    c0 += fa.x; c1 += fa.y; c2 += fb.x; c3 += fb.y;
}

// ---- layer 2 (+L3 projection): 8 lanes/node, lane j owns features 4j..4j+3.
// Per 8-edge iteration per lane: 2x int4 csr loads (head-peeled to 16B
// alignment) + 8x 8B gathers (8 lanes = full 64B row, line-coalesced).
// 4 accumulator banks. Epilogue reads W2/b2/W3 from LDS (zero VMEM).
// [R16 form — best measured 72.5us; at the random-64B-line floor]
__global__ void k_l2(const unsigned int* __restrict__ csr, const int* __restrict__ rowptr,
                     const __half* __restrict__ g, const float* __restrict__ dis,
                     const float* __restrict__ W2, const float* __restrict__ b2,
                     const float* __restrict__ W3, float* __restrict__ q, int N) {
    __shared__ float sW2[1024];                      // 4KB: [32 in][32 out]
    __shared__ float sb2[32];
    __shared__ float sW3[32];
    int tid = threadIdx.x;
    ((float4*)sW2)[tid] = ((const float4*)W2)[tid];  // 256 thr x 16B = 4KB
    if (tid < 32) { sb2[tid] = b2[tid]; sW3[tid] = W3[tid]; }
    __syncthreads();
    int t = blockIdx.x * blockDim.x + tid;
    int i = t >> 3, j = t & 7;
    if (i >= N) return;
    int beg = rowptr[i], end = rowptr[i + 1];
    const uint2* g2 = (const uint2*)g;               // [N][8] x 8B slices
    float pa0 = 0.f, pa1 = 0.f, pa2 = 0.f, pa3 = 0.f;   // bank A
    float pb0 = 0.f, pb1 = 0.f, pb2 = 0.f, pb3 = 0.f;   // bank B
    float pc0 = 0.f, pc1 = 0.f, pc2 = 0.f, pc3 = 0.f;   // bank C
    float pd0 = 0.f, pd1 = 0.f, pd2 = 0.f, pd3 = 0.f;   // bank D
    int e = beg;
    // head-peel to 4-edge (16B) alignment for int4 csr loads
    for (; e < end && (e & 3); e++) {
        int s = (int)csr[e];
        uint2 r = g2[s * 8 + j];
        acc4(pa0, pa1, pa2, pa3, r);
    }
    for (; e + 8 <= end; e += 8) {
        int4 ca = *(const int4*)(csr + e);           // slots 0..3 (aligned)
        int4 cb = *(const int4*)(csr + e + 4);       // slots 4..7
        uint2 r0 = g2[ca.x * 8 + j];
        uint2 r1 = g2[ca.y * 8 + j];
        uint2 r2 = g2[ca.z * 8 + j];
        uint2 r3 = g2[ca.w * 8 + j];
        uint2 r4 = g2[cb.x * 8 + j];
        uint2 r5 = g2[cb.y * 8 + j];
        uint2 r6 = g2[cb.z * 8 + j];
        uint2 r7 = g2[cb.w * 8 + j];
        acc4(pa0, pa1, pa2, pa3, r0);
        acc4(pb0, pb1, pb2, pb3, r1);
        acc4(pc0, pc1, pc2, pc3, r2);
        acc4(pd0, pd1, pd2, pd3, r3);
        acc4(pa0, pa1, pa2, pa3, r4);
        acc4(pb0, pb1, pb2, pb3, r5);
        acc4(pc0, pc1, pc2, pc3, r6);
        acc4(pd0, pd1, pd2, pd3, r7);
    }
    for (; e < end; e++) {
        int s = (int)csr[e];
        uint2 r = g2[s * 8 + j];
        acc4(pa0, pa1, pa2, pa3, r);
    }
    float c0 = (pa0 + pb0) + (pc0 + pd0);
    float c1 = (pa1 + pb1) + (pc1 + pd1);
    float c2 = (pa2 + pb2) + (pc2 + pd2);
    float c3 = (pa3 + pb3) + (pc3 + pd3);
    float di = dis[i];
    uint2 rs = g2[i * 8 + j];                        // self-loop slice
    float2 sa = __half22float2(*(const __half2*)&rs.x);
    float2 sb = __half22float2(*(const __half2*)&rs.y);
    float a0 = di * (c0 + sa.x);
    float a1 = di * (c1 + sa.y);
    float a2 = di * (c2 + sb.x);
    float a3 = di * (c3 + sb.y);
    // W2 matmul from LDS: lane j -> outputs m=4j..4j+3
    int m = 4 * j;
    float4 bo = *(const float4*)&sb2[m];
    float o0 = bo.x, o1 = bo.y, o2 = bo.z, o3 = bo.w;
#pragma unroll
    for (int kl = 0; kl < 8; kl++) {
        float x0 = __shfl(a0, kl, 8);                // a[4kl+0]
        float x1 = __shfl(a1, kl, 8);
        float x2 = __shfl(a2, kl, 8);
        float x3 = __shfl(a3, kl, 8);
        float4 w0 = *(const float4*)&sW2[(4 * kl + 0) * 32 + m];
        float4 w1 = *(const float4*)&sW2[(4 * kl + 1) * 32 + m];
        float4 w2 = *(const float4*)&sW2[(4 * kl + 2) * 32 + m];
        float4 w3 = *(const float4*)&sW2[(4 * kl + 3) * 32 + m];
        o0 = fmaf(x0, w0.x, fmaf(x1, w1.x, fmaf(x2, w2.x, fmaf(x3, w3.x, o0))));
        o1 = fmaf(x0, w0.y, fmaf(x1, w1.y, fmaf(x2, w2.y, fmaf(x3, w3.y, o1))));
        o2 = fmaf(x0, w0.z, fmaf(x1, w1.z, fmaf(x2, w2.z, fmaf(x3, w3.z, o2))));
        o3 = fmaf(x0, w0.w, fmaf(x1, w1.w, fmaf(x2, w2.w, fmaf(x3, w3.w, o3))));
    }
    float4 wv = *(const float4*)&sW3[m];
    float cc = fmaxf(o0, 0.f) * wv.x + fmaxf(o1, 0.f) * wv.y
             + fmaxf(o2, 0.f) * wv.z + fmaxf(o3, 0.f) * wv.w;
    cc += __shfl_xor(cc, 1, 8);
    cc += __shfl_xor(cc, 2, 8);
    cc += __shfl_xor(cc, 4, 8);
    if (j == 0) q[i] = di * cc;                      // q = dis * p
}

// ---- layer 3: node-parallel scalar q gathers (q 400KB, L2-resident)
__global__ void k_l3(const unsigned int* __restrict__ csr, const int* __restrict__ rowptr,
                     const float* __restrict__ q, const float* __restrict__ dis,
                     const float* __restrict__ b3, float* __restrict__ out, int N) {
    int t = blockIdx.x * blockDim.x + threadIdx.x;
    int i = t >> 5, j = t & 31;
    if (i >= N) return;
    int beg = rowptr[i], end = rowptr[i + 1];
    float acc = 0.f;
    for (int e = beg + j; e < end; e += 32)
        acc += q[csr[e]];
#pragma unroll
    for (int m = 16; m >= 1; m >>= 1)
        acc += __shfl_xor(acc, m, 32);
    if (j == 0) out[i] = dis[i] * (acc + q[i]) + b3[0];
}

extern "C" void kernel_launch(void* const* d_in, const int* in_sizes, int n_in,
                              void* d_out, int out_size, void* d_ws, size_t ws_size,
                              hipStream_t stream) {
    const float* x  = (const float*)d_in[0];
    const int*   ei = (const int*)d_in[1];
    const float* W1 = (const float*)d_in[2];
    const float* b1 = (const float*)d_in[3];
    const float* W2 = (const float*)d_in[4];
    const float* b2 = (const float*)d_in[5];
    const float* W3 = (const float*)d_in[6];
    const float* b3 = (const float*)d_in[7];
    float* out = (float*)d_out;

    int N = in_sizes[0] / 3;
    int E = in_sizes[1] / 2;
    const int* src = ei;
    const int* dst = ei + E;

    // workspace (all init done in-kernel; no memset needed), 256B-aligned carves
    char* w = (char*)d_ws;
#define CARVE(nbytes) w; w += (((size_t)(nbytes) + 255) & ~(size_t)255)
    int*   hist   = (int*)  CARVE((size_t)SB * NBKT * 4);   // 5.0 MB
    int*   btot   = (int*)  CARVE((size_t)MAXNB * 4);
    int*   bbase  = (int*)  CARVE((size_t)(MAXNB + 1) * 4);
    int*   rowptr = (int*)  CARVE((size_t)(N + 1) * 4);
    float* dis    = (float*)CARVE((size_t)N * 4);
    float* y4     = (float*)CARVE((size_t)N * 16);
    __half* g     = (__half*)CARVE((size_t)N * 32 * 2);     // 6.4 MB fp16
    float* q      = (float*)CARVE((size_t)N * 4);
    unsigned int* packed = (unsigned int*)CARVE((size_t)E * 4);  // 25.6 MB
#undef CARVE

    k_hist <<<SB, BLK, 0, stream>>>(dst, hist, E);
    k_scanA<<<NBKT, BLK2, 0, stream>>>(hist, btot, NBKT);
    k_scanB<<<1, MAXNB, 0, stream>>>(btot, bbase, NBKT, E);
    k_bsort<<<SB, BLK2, 0, stream>>>(src, dst, hist, btot, bbase, packed, E);
    k_sort <<<NBKT, BLK2, 0, stream>>>(packed, bbase, x, dis, (float4*)y4, rowptr, N, E);

    long long tn = (long long)N * 32;
    unsigned gn = (unsigned)((tn + BLK - 1) / BLK);
    long long tn8 = (long long)N * 8;
    unsigned gn8 = (unsigned)((tn8 + BLK - 1) / BLK);
    k_l1<<<gn,  BLK, 0, stream>>>(packed, rowptr, (const float4*)y4, dis, W1, b1, g, N);
    k_l2<<<gn8, BLK, 0, stream>>>(packed, rowptr, g, dis, W2, b2, W3, q, N);
    k_l3<<<gn,  BLK, 0, stream>>>(packed, rowptr, q, dis, b3, out, N);
}